// Round 2
// baseline (343.642 us; speedup 1.0000x reference)
//
#include <hip/hip_runtime.h>

#define TT   256
#define HID  30
#define LOG2E 1.4426950408889634f
#define HS   40   // h-row stride in bf16: 80B, rows stay 16B-aligned for b128

typedef __bf16 bf16x8_t __attribute__((ext_vector_type(8)));
typedef float  f32x4_t  __attribute__((ext_vector_type(4)));

__device__ __forceinline__ float fexp2(float x){
#if __has_builtin(__builtin_amdgcn_exp2f)
    return __builtin_amdgcn_exp2f(x);
#else
    return exp2f(x);
#endif
}
__device__ __forceinline__ float frcp(float x){
#if __has_builtin(__builtin_amdgcn_rcpf)
    return __builtin_amdgcn_rcpf(x);
#else
    return 1.f/x;
#endif
}
__device__ __forceinline__ float fsigmoid(float x){ return frcp(1.f + fexp2(-LOG2E*x)); }
__device__ __forceinline__ f32x4_t exp4(f32x4_t v){
    f32x4_t e; e[0]=fexp2(v[0]); e[1]=fexp2(v[1]); e[2]=fexp2(v[2]); e[3]=fexp2(v[3]); return e;
}
__device__ __forceinline__ f32x4_t rcp4(f32x4_t v){
    f32x4_t r; r[0]=frcp(v[0]); r[1]=frcp(v[1]); r[2]=frcp(v[2]); r[3]=frcp(v[3]); return r;
}
__device__ __forceinline__ f32x4_t splat4(float v){ f32x4_t r = {v,v,v,v}; return r; }

// Accs arrive pre-scaled into exp2 domain (scale folded into bf16 weights):
//   aI,aF,aO = -LOG2E*z ; aG = +2*LOG2E*z
// Merged-rcp activation (28 trans insts per gate-set instead of 32):
//   D1 = 1+eF ; D2 = (1+eI)(1+eG) ; r = 1/(D1*D2)
//   f = r*D2 ; i*tanh(zg) = (eG-1)*r*D1 ; c = f*c + p
//   h = o*tanh(c) = (eC-1)/((1+eO)(1+eC)), eC = e^{2c}
__device__ __forceinline__ f32x4_t lstm_act(f32x4_t aI, f32x4_t aF, f32x4_t aG,
                                            f32x4_t aO, f32x4_t& cst){
    f32x4_t eI = exp4(aI);
    f32x4_t eF = exp4(aF);
    f32x4_t eG = exp4(aG);
    f32x4_t eO = exp4(aO);
    f32x4_t D1 = eF + 1.f;
    f32x4_t tG = eG + 1.f;
    f32x4_t D2 = (eI + 1.f) * tG;
    f32x4_t r  = rcp4(D1*D2);
    f32x4_t f  = r*D2;                 // 1/(1+eF)
    f32x4_t p  = (eG - 1.f) * (r*D1);  // i*tanh(zg)
    cst = f*cst + p;
    f32x4_t cc;                        // clamp so e^{2c} can't overflow (v_med3)
    cc[0]=fminf(fmaxf(cst[0],-30.f),30.f);
    cc[1]=fminf(fmaxf(cst[1],-30.f),30.f);
    cc[2]=fminf(fmaxf(cst[2],-30.f),30.f);
    cc[3]=fminf(fmaxf(cst[3],-30.f),30.f);
    f32x4_t eC = exp4(cc * (2.f*LOG2E));
    f32x4_t tC = eC + 1.f;
    return (eC - 1.f) * rcp4((eO + 1.f)*tC);
}

// 256-thread block = 2 independent 16-row sub-teams {L0-full wave, L1-full wave}.
// Block covers 32 rows; grid 256 = 1 block/CU, 1 wave/SIMD.
// Each wave owns a full layer for its rows: A-operand is shared across unit
// halves, so 1 ds_read feeds 8 (L0) / 16 (L1) MFMAs. Skewed pipeline (L1
// trails L0 by 1 step), double-buffered bf16 h tiles, 1 barrier per step.
__global__ __launch_bounds__(256, 1)
void lstm_fused(const float* __restrict__ x,
    const float* __restrict__ Wih0, const float* __restrict__ Whh0,
    const float* __restrict__ bih0, const float* __restrict__ bhh0,
    const float* __restrict__ Wih1, const float* __restrict__ Whh1,
    const float* __restrict__ bih1, const float* __restrict__ bhh1,
    const float* __restrict__ Wfc1, const float* __restrict__ bfc1,
    const float* __restrict__ Wfc2, const float* __restrict__ bfc2,
    const float* __restrict__ Wfc3, const float* __restrict__ bfc3,
    float* __restrict__ out)
{
    __shared__ __align__(16) __bf16 h0f[2][2][16][HS];  // [grp][buf][row][k]; k=30,31: x0,x1
    __shared__ __align__(16) __bf16 h1f[2][2][16][HS];  // k>=30 stays 0
    __shared__ float h1_last[2][16][32];
    __shared__ float zbuf[32][64];
    __shared__ float z2buf[32][32];

    const int tid  = threadIdx.x;
    const int lane = tid & 63;
    const int wv   = tid >> 6;         // 0..3
    const int grp  = wv >> 1;          // row sub-team
    const int role = wv & 1;           // 0: layer0, 1: layer1
    const int n    = lane & 15;
    const int q    = lane >> 4;
    const int q4   = q*4;
    const int bbase = blockIdx.x * 32;
    const int rbase = bbase + grp*16;

    // ---- resident per-gate B-fragments, scale folded into bf16 weights ----
    // wA: L0 = Whh0+Wih0(x0,x1 at k=30,31) | L1 = Wih1 (vs h0)
    // wB: L1 = Whh1 (vs h1); unused for L0
    bf16x8_t wA[2][4], wB[2][4];
    float bv[2][4], wx[2][4];
    {
        const float scl[4] = {-LOG2E, -LOG2E, 2.f*LOG2E, -LOG2E}; // i,f,g,o
        #pragma unroll
        for (int h = 0; h < 2; ++h) {
            const int u = h*16 + n;
            const bool ok = (u < HID);
            const int uq = ok ? u : 0;
            #pragma unroll
            for (int g = 0; g < 4; ++g) {
                const int row = g*HID + uq;
                const float sg = scl[g];
                bf16x8_t va{}, vb{};
                #pragma unroll
                for (int j = 0; j < 8; ++j) {
                    int k = q*8 + j;
                    float a = 0.f, b = 0.f;
                    if (ok) {
                        if (role == 0) {
                            if (k < HID)      a = Whh0[row*HID + k];
                            else if (k < 32)  a = Wih0[row*3 + (k - HID)];
                        } else {
                            if (k < HID) { a = Wih1[row*HID + k];  b = Whh1[row*HID + k]; }
                        }
                    }
                    va[j] = (__bf16)(sg*a);
                    vb[j] = (__bf16)(sg*b);
                }
                wA[h][g] = va;  wB[h][g] = vb;
                float bb = 0.f, ww = 0.f;
                if (ok) {
                    bb = role ? (bih1[row] + bhh1[row]) : (bih0[row] + bhh0[row]);
                    if (role == 0) ww = Wih0[row*3 + 2];
                }
                bv[h][g] = sg*bb;  wx[h][g] = sg*ww;
            }
        }
    }

    f32x4_t cst0 = {0.f,0.f,0.f,0.f};
    f32x4_t cst1 = {0.f,0.f,0.f,0.f};

    for (int i = tid; i < 2*2*16*HS; i += 256) {
        (&h0f[0][0][0][0])[i] = (__bf16)0.f;
        (&h1f[0][0][0][0])[i] = (__bf16)0.f;
    }
    __syncthreads();
    if (tid < 64) {    // x0,x1(t=0) into prologue read-buffer h0f[g][1]
        int g2 = tid >> 5, m = (tid >> 1) & 15, c = tid & 1;
        h0f[g2][1][m][30+c] = (__bf16)x[(size_t)(bbase + g2*16 + m)*(TT*3) + c];
    }
    __syncthreads();

    // x addressing: SGPR base + fixed VGPR offsets (L0 waves only)
    const float* xB = x + (size_t)rbase*(TT*3);
    const int xo2  = q4*(TT*3) + 2;               // + r*TT*3 for r=0..3
    const int xo01 = ((lane>>1)&15)*(TT*3) + (lane&1);
    f32x4_t x2v = {0.f,0.f,0.f,0.f};
    if (role == 0) {   // x2(t=0)
        x2v[0]=xB[xo2]; x2v[1]=xB[xo2+TT*3]; x2v[2]=xB[xo2+2*TT*3]; x2v[3]=xB[xo2+3*TT*3];
    }

#define STEP(S, RB, WB, FIRST) do {                                            \
    if (role == 0) {                                                           \
        bf16x8_t A0 = *(const bf16x8_t*)(&h0f[grp][RB][n][q*8]);               \
        f32x4_t aI0 = __builtin_amdgcn_mfma_f32_16x16x32_bf16(A0, wA[0][0], x2v*wx[0][0] + bv[0][0], 0,0,0); \
        f32x4_t aF0 = __builtin_amdgcn_mfma_f32_16x16x32_bf16(A0, wA[0][1], x2v*wx[0][1] + bv[0][1], 0,0,0); \
        f32x4_t aG0 = __builtin_amdgcn_mfma_f32_16x16x32_bf16(A0, wA[0][2], x2v*wx[0][2] + bv[0][2], 0,0,0); \
        f32x4_t aO0 = __builtin_amdgcn_mfma_f32_16x16x32_bf16(A0, wA[0][3], x2v*wx[0][3] + bv[0][3], 0,0,0); \
        f32x4_t aI1 = __builtin_amdgcn_mfma_f32_16x16x32_bf16(A0, wA[1][0], x2v*wx[1][0] + bv[1][0], 0,0,0); \
        f32x4_t aF1 = __builtin_amdgcn_mfma_f32_16x16x32_bf16(A0, wA[1][1], x2v*wx[1][1] + bv[1][1], 0,0,0); \
        f32x4_t aG1 = __builtin_amdgcn_mfma_f32_16x16x32_bf16(A0, wA[1][2], x2v*wx[1][2] + bv[1][2], 0,0,0); \
        f32x4_t aO1 = __builtin_amdgcn_mfma_f32_16x16x32_bf16(A0, wA[1][3], x2v*wx[1][3] + bv[1][3], 0,0,0); \
        const int tpre = ((S)+2 < TT) ? (S)+2 : TT-1;                          \
        const float* xs = xB + 3*tpre;                                         \
        f32x4_t x2n;                                                           \
        x2n[0]=xs[xo2]; x2n[1]=xs[xo2+TT*3];                                   \
        x2n[2]=xs[xo2+2*TT*3]; x2n[3]=xs[xo2+3*TT*3];                          \
        float x01v = 0.f;                                                      \
        if (lane < 32) x01v = xs[xo01];                                        \
        f32x4_t h0v = lstm_act(aI0, aF0, aG0, aO0, cst0);                      \
        f32x4_t h1v = lstm_act(aI1, aF1, aG1, aO1, cst1);                      \
        h0f[WB_ grp][q4  ][n] = (__bf16)h0v[0];                                \
        h0f[WB_ grp][q4+1][n] = (__bf16)h0v[1];                                \
        h0f[WB_ grp][q4+2][n] = (__bf16)h0v[2];                                \
        h0f[WB_ grp][q4+3][n] = (__bf16)h0v[3];                                \
        if (n < 14) {                                                          \
            h0f[WB_ grp][q4  ][16+n] = (__bf16)h1v[0];                         \
            h0f[WB_ grp][q4+1][16+n] = (__bf16)h1v[1];                         \
            h0f[WB_ grp][q4+2][16+n] = (__bf16)h1v[2];                         \
            h0f[WB_ grp][q4+3][16+n] = (__bf16)h1v[3];                         \
        }                                                                      \
        if (lane < 32) h0f[WB_ grp][(lane>>1)&15][30+(lane&1)] = (__bf16)x01v; \
        x2v = x2n;                                                             \
    } else if (!(FIRST)) {                                                     \
        bf16x8_t A1 = *(const bf16x8_t*)(&h0f[grp][RB][n][q*8]);               \
        bf16x8_t A2 = *(const bf16x8_t*)(&h1f[grp][RB][n][q*8]);               \
        f32x4_t aI0 = __builtin_amdgcn_mfma_f32_16x16x32_bf16(A2, wB[0][0], splat4(bv[0][0]), 0,0,0); \
        f32x4_t aF0 = __builtin_amdgcn_mfma_f32_16x16x32_bf16(A2, wB[0][1], splat4(bv[0][1]), 0,0,0); \
        f32x4_t aG0 = __builtin_amdgcn_mfma_f32_16x16x32_bf16(A2, wB[0][2], splat4(bv[0][2]), 0,0,0); \
        f32x4_t aO0 = __builtin_amdgcn_mfma_f32_16x16x32_bf16(A2, wB[0][3], splat4(bv[0][3]), 0,0,0); \
        f32x4_t aI1 = __builtin_amdgcn_mfma_f32_16x16x32_bf16(A2, wB[1][0], splat4(bv[1][0]), 0,0,0); \
        f32x4_t aF1 = __builtin_amdgcn_mfma_f32_16x16x32_bf16(A2, wB[1][1], splat4(bv[1][1]), 0,0,0); \
        f32x4_t aG1 = __builtin_amdgcn_mfma_f32_16x16x32_bf16(A2, wB[1][2], splat4(bv[1][2]), 0,0,0); \
        f32x4_t aO1 = __builtin_amdgcn_mfma_f32_16x16x32_bf16(A2, wB[1][3], splat4(bv[1][3]), 0,0,0); \
        aI0 = __builtin_amdgcn_mfma_f32_16x16x32_bf16(A1, wA[0][0], aI0, 0,0,0); \
        aF0 = __builtin_amdgcn_mfma_f32_16x16x32_bf16(A1, wA[0][1], aF0, 0,0,0); \
        aG0 = __builtin_amdgcn_mfma_f32_16x16x32_bf16(A1, wA[0][2], aG0, 0,0,0); \
        aO0 = __builtin_amdgcn_mfma_f32_16x16x32_bf16(A1, wA[0][3], aO0, 0,0,0); \
        aI1 = __builtin_amdgcn_mfma_f32_16x16x32_bf16(A1, wA[1][0], aI1, 0,0,0); \
        aF1 = __builtin_amdgcn_mfma_f32_16x16x32_bf16(A1, wA[1][1], aF1, 0,0,0); \
        aG1 = __builtin_amdgcn_mfma_f32_16x16x32_bf16(A1, wA[1][2], aG1, 0,0,0); \
        aO1 = __builtin_amdgcn_mfma_f32_16x16x32_bf16(A1, wA[1][3], aO1, 0,0,0); \
        f32x4_t h0v = lstm_act(aI0, aF0, aG0, aO0, cst0);                      \
        f32x4_t h1v = lstm_act(aI1, aF1, aG1, aO1, cst1);                      \
        h1f[WB_ grp][q4  ][n] = (__bf16)h0v[0];                                \
        h1f[WB_ grp][q4+1][n] = (__bf16)h0v[1];                                \
        h1f[WB_ grp][q4+2][n] = (__bf16)h0v[2];                                \
        h1f[WB_ grp][q4+3][n] = (__bf16)h0v[3];                                \
        if (n < 14) {                                                          \
            h1f[WB_ grp][q4  ][16+n] = (__bf16)h1v[0];                         \
            h1f[WB_ grp][q4+1][16+n] = (__bf16)h1v[1];                         \
            h1f[WB_ grp][q4+2][16+n] = (__bf16)h1v[2];                         \
            h1f[WB_ grp][q4+3][16+n] = (__bf16)h1v[3];                         \
        }                                                                      \
        if ((S) == TT-1) {                                                     \
            h1_last[grp][q4  ][n] = h0v[0];                                    \
            h1_last[grp][q4+1][n] = h0v[1];                                    \
            h1_last[grp][q4+2][n] = h0v[2];                                    \
            h1_last[grp][q4+3][n] = h0v[3];                                    \
            if (n < 14) {                                                      \
                h1_last[grp][q4  ][16+n] = h1v[0];                             \
                h1_last[grp][q4+1][16+n] = h1v[1];                             \
                h1_last[grp][q4+2][16+n] = h1v[2];                             \
                h1_last[grp][q4+3][16+n] = h1v[3];                             \
            }                                                                  \
        }                                                                      \
    }                                                                          \
    __syncthreads();                                                           \
} while (0)

#define WB_ grp

    {
        #define PROLOG_RB 1
        // prologue: layer0 t=0 only
        #undef PROLOG_RB
    }

    // NOTE: WB_/RB are spliced as literal buffer indices via the macro args.
    // (WB_ grp trick above expands to [grp] indexing with WB literal baked in
    //  through the redefinitions below.)
#undef WB_

#define STEPX(S, RB, WB, FIRST)                                                \
    do {                                                                       \
        _Pragma("clang diagnostic push")                                       \
        STEP_IMPL(S, RB, WB, FIRST);                                           \
        _Pragma("clang diagnostic pop")                                        \
    } while (0)

    // --- expand STEP with literal RB/WB ---
#define WB_ 0][
#undef WB_

    // Simpler: re-instantiate with explicit buffer indices.
#undef STEP
#define STEP(S, RB, WB, FIRST) do {                                            \
    if (role == 0) {                                                           \
        bf16x8_t A0 = *(const bf16x8_t*)(&h0f[grp][RB][n][q*8]);               \
        f32x4_t aI0 = __builtin_amdgcn_mfma_f32_16x16x32_bf16(A0, wA[0][0], x2v*wx[0][0] + bv[0][0], 0,0,0); \
        f32x4_t aF0 = __builtin_amdgcn_mfma_f32_16x16x32_bf16(A0, wA[0][1], x2v*wx[0][1] + bv[0][1], 0,0,0); \
        f32x4_t aG0 = __builtin_amdgcn_mfma_f32_16x16x32_bf16(A0, wA[0][2], x2v*wx[0][2] + bv[0][2], 0,0,0); \
        f32x4_t aO0 = __builtin_amdgcn_mfma_f32_16x16x32_bf16(A0, wA[0][3], x2v*wx[0][3] + bv[0][3], 0,0,0); \
        f32x4_t aI1 = __builtin_amdgcn_mfma_f32_16x16x32_bf16(A0, wA[1][0], x2v*wx[1][0] + bv[1][0], 0,0,0); \
        f32x4_t aF1 = __builtin_amdgcn_mfma_f32_16x16x32_bf16(A0, wA[1][1], x2v*wx[1][1] + bv[1][1], 0,0,0); \
        f32x4_t aG1 = __builtin_amdgcn_mfma_f32_16x16x32_bf16(A0, wA[1][2], x2v*wx[1][2] + bv[1][2], 0,0,0); \
        f32x4_t aO1 = __builtin_amdgcn_mfma_f32_16x16x32_bf16(A0, wA[1][3], x2v*wx[1][3] + bv[1][3], 0,0,0); \
        const int tpre = ((S)+2 < TT) ? (S)+2 : TT-1;                          \
        const float* xs = xB + 3*tpre;                                         \
        f32x4_t x2n;                                                           \
        x2n[0]=xs[xo2]; x2n[1]=xs[xo2+TT*3];                                   \
        x2n[2]=xs[xo2+2*TT*3]; x2n[3]=xs[xo2+3*TT*3];                          \
        float x01v = 0.f;                                                      \
        if (lane < 32) x01v = xs[xo01];                                        \
        f32x4_t h0v = lstm_act(aI0, aF0, aG0, aO0, cst0);                      \
        f32x4_t h1v = lstm_act(aI1, aF1, aG1, aO1, cst1);                      \
        h0f[grp][WB][q4  ][n] = (__bf16)h0v[0];                                \
        h0f[grp][WB][q4+1][n] = (__bf16)h0v[1];                                \
        h0f[grp][WB][q4+2][n] = (__bf16)h0v[2];                                \
        h0f[grp][WB][q4+3][n] = (__bf16)h0v[3];                                \
        if (n < 14) {                                                          \
            h0f[grp][WB][q4  ][16+n] = (__bf16)h1v[0];                         \
            h0f[grp][WB][q4+1][16+n] = (__bf16)h1v[1];                         \
            h0f[grp][WB][q4+2][16+n] = (__bf16)h1v[2];                         \
            h0f[grp][WB][q4+3][16+n] = (__bf16)h1v[3];                         \
        }                                                                      \
        if (lane < 32) h0f[grp][WB][(lane>>1)&15][30+(lane&1)] = (__bf16)x01v; \
        x2v = x2n;                                                             \
    } else if (!(FIRST)) {                                                     \
        bf16x8_t A1 = *(const bf16x8_t*)(&h0f[grp][RB][n][q*8]);               \
        bf16x8_t A2 = *(const bf16x8_t*)(&h1f[grp][RB][n][q*8]);               \
        f32x4_t aI0 = __builtin_amdgcn_mfma_f32_16x16x32_bf16(A2, wB[0][0], splat4(bv[0][0]), 0,0,0); \
        f32x4_t aF0 = __builtin_amdgcn_mfma_f32_16x16x32_bf16(A2, wB[0][1], splat4(bv[0][1]), 0,0,0); \
        f32x4_t aG0 = __builtin_amdgcn_mfma_f32_16x16x32_bf16(A2, wB[0][2], splat4(bv[0][2]), 0,0,0); \
        f32x4_t aO0 = __builtin_amdgcn_mfma_f32_16x16x32_bf16(A2, wB[0][3], splat4(bv[0][3]), 0,0,0); \
        f32x4_t aI1 = __builtin_amdgcn_mfma_f32_16x16x32_bf16(A2, wB[1][0], splat4(bv[1][0]), 0,0,0); \
        f32x4_t aF1 = __builtin_amdgcn_mfma_f32_16x16x32_bf16(A2, wB[1][1], splat4(bv[1][1]), 0,0,0); \
        f32x4_t aG1 = __builtin_amdgcn_mfma_f32_16x16x32_bf16(A2, wB[1][2], splat4(bv[1][2]), 0,0,0); \
        f32x4_t aO1 = __builtin_amdgcn_mfma_f32_16x16x32_bf16(A2, wB[1][3], splat4(bv[1][3]), 0,0,0); \
        aI0 = __builtin_amdgcn_mfma_f32_16x16x32_bf16(A1, wA[0][0], aI0, 0,0,0); \
        aF0 = __builtin_amdgcn_mfma_f32_16x16x32_bf16(A1, wA[0][1], aF0, 0,0,0); \
        aG0 = __builtin_amdgcn_mfma_f32_16x16x32_bf16(A1, wA[0][2], aG0, 0,0,0); \
        aO0 = __builtin_amdgcn_mfma_f32_16x16x32_bf16(A1, wA[0][3], aO0, 0,0,0); \
        aI1 = __builtin_amdgcn_mfma_f32_16x16x32_bf16(A1, wA[1][0], aI1, 0,0,0); \
        aF1 = __builtin_amdgcn_mfma_f32_16x16x32_bf16(A1, wA[1][1], aF1, 0,0,0); \
        aG1 = __builtin_amdgcn_mfma_f32_16x16x32_bf16(A1, wA[1][2], aG1, 0,0,0); \
        aO1 = __builtin_amdgcn_mfma_f32_16x16x32_bf16(A1, wA[1][3], aO1, 0,0,0); \
        f32x4_t h0v = lstm_act(aI0, aF0, aG0, aO0, cst0);                      \
        f32x4_t h1v = lstm_act(aI1, aF1, aG1, aO1, cst1);                      \
        h1f[grp][WB][q4  ][n] = (__bf16)h0v[0];                                \
        h1f[grp][WB][q4+1][n] = (__bf16)h0v[1];                                \
        h1f[grp][WB][q4+2][n] = (__bf16)h0v[2];                                \
        h1f[grp][WB][q4+3][n] = (__bf16)h0v[3];                                \
        if (n < 14) {                                                          \
            h1f[grp][WB][q4  ][16+n] = (__bf16)h1v[0];                         \
            h1f[grp][WB][q4+1][16+n] = (__bf16)h1v[1];                         \
            h1f[grp][WB][q4+2][16+n] = (__bf16)h1v[2];                         \
            h1f[grp][WB][q4+3][16+n] = (__bf16)h1v[3];                         \
        }                                                                      \
        if ((S) == TT-1) {                                                     \
            h1_last[grp][q4  ][n] = h0v[0];                                    \
            h1_last[grp][q4+1][n] = h0v[1];                                    \
            h1_last[grp][q4+2][n] = h0v[2];                                    \
            h1_last[grp][q4+3][n] = h0v[3];                                    \
            if (n < 14) {                                                      \
                h1_last[grp][q4  ][16+n] = h1v[0];                             \
                h1_last[grp][q4+1][16+n] = h1v[1];                             \
                h1_last[grp][q4+2][16+n] = h1v[2];                             \
                h1_last[grp][q4+3][16+n] = h1v[3];                             \
            }                                                                  \
        }                                                                      \
    }                                                                          \
    __syncthreads();                                                           \
} while (0)

    STEP(-1, 1, 0, 1);          // prologue: layer0 t=0 only
    #pragma unroll 1
    for (int s = 0; s < TT; s += 2) {
        STEP(s,   0, 1, 0);
        STEP(s+1, 1, 0, 0);
    }
#undef STEP

    // ---- FC head (256 threads, 32 rows) ----
    #pragma unroll
    for (int rep = 0; rep < 8; ++rep) {
        int idx = tid + rep*256;          // 32*64 outputs
        int m = idx >> 6, uu = idx & 63;
        float a = bfc1[uu];
        for (int k = 0; k < HID; ++k) a += h1_last[m>>4][m&15][k] * Wfc1[uu*HID+k];
        zbuf[m][uu] = fmaxf(a, 0.f);
    }
    __syncthreads();
    #pragma unroll
    for (int rep = 0; rep < 4; ++rep) {
        int idx = tid + rep*256;          // 32*32 outputs
        int m = idx >> 5, v = idx & 31;
        float a = bfc2[v];
        for (int k = 0; k < 64; ++k) a += zbuf[m][k] * Wfc2[v*64+k];
        z2buf[m][v] = fmaxf(a, 0.f);
    }
    __syncthreads();
    if (tid < 32) {
        float a = bfc3[0];
        for (int k = 0; k < 32; ++k) a += z2buf[tid][k] * Wfc3[k];
        out[bbase + tid] = fsigmoid(a);
    }
}

extern "C" void kernel_launch(void* const* d_in, const int* in_sizes, int n_in,
                              void* d_out, int out_size, void* d_ws, size_t ws_size,
                              hipStream_t stream) {
    const float* x    = (const float*)d_in[0];
    const float* Wih0 = (const float*)d_in[1];
    const float* Whh0 = (const float*)d_in[2];
    const float* bih0 = (const float*)d_in[3];
    const float* bhh0 = (const float*)d_in[4];
    const float* Wih1 = (const float*)d_in[5];
    const float* Whh1 = (const float*)d_in[6];
    const float* bih1 = (const float*)d_in[7];
    const float* bhh1 = (const float*)d_in[8];
    const float* Wfc1 = (const float*)d_in[9];
    const float* bfc1 = (const float*)d_in[10];
    const float* Wfc2 = (const float*)d_in[11];
    const float* bfc2 = (const float*)d_in[12];
    const float* Wfc3 = (const float*)d_in[13];
    const float* bfc3 = (const float*)d_in[14];
    float* outp = (float*)d_out;

    hipLaunchKernelGGL(lstm_fused, dim3(256), dim3(256), 0, stream,
        x, Wih0, Whh0, bih0, bhh0, Wih1, Whh1, bih1, bhh1,
        Wfc1, bfc1, Wfc2, bfc2, Wfc3, bfc3, outp);
}

// Round 3
// 275.819 us; speedup vs baseline: 1.2459x; 1.2459x over previous
//
#include <hip/hip_runtime.h>

#define TT   256
#define HID  30
#define LOG2E 1.4426950408889634f
#define HS   40   // h-row stride in bf16: 80B, rows stay 16B-aligned for b128

typedef __bf16 bf16x8_t __attribute__((ext_vector_type(8)));
typedef float  f32x4_t  __attribute__((ext_vector_type(4)));

__device__ __forceinline__ float fexp2(float x){
#if __has_builtin(__builtin_amdgcn_exp2f)
    return __builtin_amdgcn_exp2f(x);
#else
    return exp2f(x);
#endif
}
__device__ __forceinline__ float frcp(float x){
#if __has_builtin(__builtin_amdgcn_rcpf)
    return __builtin_amdgcn_rcpf(x);
#else
    return 1.f/x;
#endif
}
__device__ __forceinline__ float fsigmoid(float x){ return frcp(1.f + fexp2(-LOG2E*x)); }
__device__ __forceinline__ f32x4_t exp4(f32x4_t v){
    f32x4_t e; e[0]=fexp2(v[0]); e[1]=fexp2(v[1]); e[2]=fexp2(v[2]); e[3]=fexp2(v[3]); return e;
}
__device__ __forceinline__ f32x4_t rcp4(f32x4_t v){
    f32x4_t r; r[0]=frcp(v[0]); r[1]=frcp(v[1]); r[2]=frcp(v[2]); r[3]=frcp(v[3]); return r;
}
__device__ __forceinline__ f32x4_t splat4(float v){ f32x4_t r = {v,v,v,v}; return r; }

// Accs arrive pre-scaled into exp2 domain (scale folded into bf16 weights):
//   aI,aF,aO = -LOG2E*z ; aG = +2*LOG2E*z
// Merged-rcp activation: 28 trans insts (20 exp + 8 rcp) per 4-vec:
//   D1 = 1+eF ; D2 = (1+eI)(1+eG) ; r = 1/(D1*D2)
//   f = r*D2 = sigmoid(zf) ; p = (eG-1)*r*D1 = i*tanh(zg) ; c = f*c + p
//   h = o*tanh(c) = (eC-1)/((1+eO)(1+eC)), eC = e^{2c}
__device__ __forceinline__ f32x4_t lstm_act(f32x4_t aI, f32x4_t aF, f32x4_t aG,
                                            f32x4_t aO, f32x4_t& cst){
    f32x4_t eI = exp4(aI);
    f32x4_t eF = exp4(aF);
    f32x4_t eG = exp4(aG);
    f32x4_t eO = exp4(aO);
    f32x4_t D1 = eF + 1.f;
    f32x4_t tG = eG + 1.f;
    f32x4_t D2 = eI*tG + tG;           // (1+eI)(1+eG), fma
    f32x4_t r  = rcp4(D1*D2);
    f32x4_t f  = r*D2;                 // 1/(1+eF)
    f32x4_t p  = (eG - 1.f) * (r*D1);  // i*tanh(zg)
    cst = f*cst + p;
    f32x4_t cc;                        // clamp so e^{2c} can't overflow (v_med3)
    cc[0]=fminf(fmaxf(cst[0],-30.f),30.f);
    cc[1]=fminf(fmaxf(cst[1],-30.f),30.f);
    cc[2]=fminf(fmaxf(cst[2],-30.f),30.f);
    cc[3]=fminf(fmaxf(cst[3],-30.f),30.f);
    f32x4_t eC = exp4(cc * (2.f*LOG2E));
    f32x4_t tC = eC + 1.f;
    f32x4_t dn = eO*tC + tC;           // (1+eO)(1+eC), fma
    return (eC - 1.f) * rcp4(dn);
}

// R1 structure (213 us): 256-thread blocks, 4 waves: wv0,1 = layer0 (unit
// halves 0-15 / 16-29), wv2,3 = layer1. Grid 512, 2 blocks/CU, 2 waves/SIMD.
// Skewed pipeline (layer1 trails layer0 by 1 step), double-buffered bf16 h
// tiles in LDS, 1 barrier per step.
// R3 additions: (a) co-resident blocks (i, i+256) are de-phased by ~half a
// step via s_sleep so their barrier stalls anti-phase on the shared SIMDs;
// (b) merged-rcp activation; (c) branchless x01 side loads.
__global__ __launch_bounds__(256, 2)
void lstm_fused(const float* __restrict__ x,
    const float* __restrict__ Wih0, const float* __restrict__ Whh0,
    const float* __restrict__ bih0, const float* __restrict__ bhh0,
    const float* __restrict__ Wih1, const float* __restrict__ Whh1,
    const float* __restrict__ bih1, const float* __restrict__ bhh1,
    const float* __restrict__ Wfc1, const float* __restrict__ bfc1,
    const float* __restrict__ Wfc2, const float* __restrict__ bfc2,
    const float* __restrict__ Wfc3, const float* __restrict__ bfc3,
    float* __restrict__ out)
{
    __shared__ __align__(16) __bf16 h0f[2][16][HS];  // k=30,31: x0,x1 slots
    __shared__ __align__(16) __bf16 h1f[2][16][HS];  // k>=30 irrelevant (zero weights)
    __shared__ float h1_last[16*32];
    __shared__ float zbuf[16*64];
    __shared__ float z2buf[16*32];

    const int tid  = threadIdx.x;
    const int lane = tid & 63;
    const int wv   = tid >> 6;         // 0..3
    const int lay  = wv >> 1;          // 0: layer0, 1: layer1
    const int uh   = wv & 1;           // unit half
    const int n    = lane & 15;
    const int q    = lane >> 4;
    const int q4   = q*4;
    const int u    = uh*16 + n;        // hidden unit (col)
    const bool colok = (u < HID);
    const int uq   = colok ? u : 0;
    const int bbase = blockIdx.x * 16;

    // ---- resident per-gate B-fragments, scale folded into bf16 weights ----
    bf16x8_t fA[4], fB[4];             // fA: Whh0+Wih0 | Wih1 ; fB: Whh1 (layer1)
    float bv[4], wx[4];
    {
        const float scl[4] = {-LOG2E, -LOG2E, 2.f*LOG2E, -LOG2E}; // i,f,g,o
        #pragma unroll
        for (int g = 0; g < 4; ++g) {
            const int row = g*HID + uq;
            const float sg = scl[g];
            bf16x8_t va{}, vb{};
            #pragma unroll
            for (int j = 0; j < 8; ++j) {
                int k = q*8 + j;
                float a = 0.f, b = 0.f;
                if (colok) {
                    if (lay == 0) {
                        if (k < HID)      a = Whh0[row*HID + k];
                        else if (k < 32)  a = Wih0[row*3 + (k - HID)];
                    } else {
                        if (k < HID) { a = Wih1[row*HID + k];  b = Whh1[row*HID + k]; }
                    }
                }
                va[j] = (__bf16)(sg*a);
                vb[j] = (__bf16)(sg*b);
            }
            fA[g] = va;  fB[g] = vb;
            float bb = 0.f, ww = 0.f;
            if (colok) {
                bb = lay ? (bih1[row] + bhh1[row]) : (bih0[row] + bhh0[row]);
                if (lay == 0) ww = Wih0[row*3 + 2];
            }
            bv[g] = sg*bb;  wx[g] = sg*ww;
        }
    }

    f32x4_t cst = {0.f,0.f,0.f,0.f};

    for (int i = tid; i < 2*16*HS; i += 256) {
        (&h0f[0][0][0])[i] = (__bf16)0.f;
        (&h1f[0][0][0])[i] = (__bf16)0.f;
    }
    __syncthreads();
    if (tid < 32) {    // x0,x1(t=0) into prologue read-buffer h0f[1]
        int m = tid >> 1, cc = tid & 1;
        h0f[1][m][30+cc] = (__bf16)x[(size_t)(bbase+m)*(TT*3) + cc];
    }
    __syncthreads();

    // De-phase the co-resident partner block (pairs differ in bit 8 of
    // blockIdx: same XCD (bit 0-2), same CU slot). One-time ~1K-cycle shift;
    // no inter-block sync exists to re-lock them.
    if (blockIdx.x & 256) {
        __builtin_amdgcn_s_sleep(16);
    }

    // x addressing: SGPR base + fixed VGPR offsets
    const float* xB = x + (size_t)bbase*(TT*3);
    const int xo2  = q4*(TT*3) + 2;                    // + r*TT*3 for r=0..3
    const int xo01 = (((tid>>1)&15))*(TT*3) + (tid&1); // lanes 32+ duplicate 0-31
    f32x4_t x2 = {0.f,0.f,0.f,0.f};
    if (lay == 0) {   // x2(t=0)
        x2[0]=xB[xo2]; x2[1]=xB[xo2+TT*3]; x2[2]=xB[xo2+2*TT*3]; x2[3]=xB[xo2+3*TT*3];
    }

#define STEP(S, RB, WB, FIRST) do {                                            \
    if (lay == 0) {                                                            \
        bf16x8_t A0 = *(const bf16x8_t*)(&h0f[RB][n][q*8]);                    \
        f32x4_t aI = __builtin_amdgcn_mfma_f32_16x16x32_bf16(A0, fA[0], x2*wx[0] + bv[0], 0,0,0); \
        f32x4_t aF = __builtin_amdgcn_mfma_f32_16x16x32_bf16(A0, fA[1], x2*wx[1] + bv[1], 0,0,0); \
        f32x4_t aG = __builtin_amdgcn_mfma_f32_16x16x32_bf16(A0, fA[2], x2*wx[2] + bv[2], 0,0,0); \
        f32x4_t aO = __builtin_amdgcn_mfma_f32_16x16x32_bf16(A0, fA[3], x2*wx[3] + bv[3], 0,0,0); \
        const int tpre = ((S)+2 < TT) ? (S)+2 : TT-1;                          \
        const float* xs = xB + 3*tpre;                                         \
        f32x4_t x2n;                                                           \
        x2n[0]=xs[xo2]; x2n[1]=xs[xo2+TT*3];                                   \
        x2n[2]=xs[xo2+2*TT*3]; x2n[3]=xs[xo2+3*TT*3];                          \
        float x01v = xs[xo01];                                                 \
        f32x4_t h = lstm_act(aI, aF, aG, aO, cst);                             \
        if (colok) {                                                           \
            h0f[WB][q4  ][u] = (__bf16)h[0];                                   \
            h0f[WB][q4+1][u] = (__bf16)h[1];                                   \
            h0f[WB][q4+2][u] = (__bf16)h[2];                                   \
            h0f[WB][q4+3][u] = (__bf16)h[3];                                   \
        }                                                                      \
        h0f[WB][(tid>>1)&15][30+(tid&1)] = (__bf16)x01v;                       \
        x2 = x2n;                                                              \
    } else if (!(FIRST)) {                                                     \
        bf16x8_t A1 = *(const bf16x8_t*)(&h0f[RB][n][q*8]);                    \
        bf16x8_t A2 = *(const bf16x8_t*)(&h1f[RB][n][q*8]);                    \
        f32x4_t aI = __builtin_amdgcn_mfma_f32_16x16x32_bf16(A2, fB[0], splat4(bv[0]), 0,0,0); \
        aI         = __builtin_amdgcn_mfma_f32_16x16x32_bf16(A1, fA[0], aI, 0,0,0); \
        f32x4_t aF = __builtin_amdgcn_mfma_f32_16x16x32_bf16(A2, fB[1], splat4(bv[1]), 0,0,0); \
        aF         = __builtin_amdgcn_mfma_f32_16x16x32_bf16(A1, fA[1], aF, 0,0,0); \
        f32x4_t aG = __builtin_amdgcn_mfma_f32_16x16x32_bf16(A2, fB[2], splat4(bv[2]), 0,0,0); \
        aG         = __builtin_amdgcn_mfma_f32_16x16x32_bf16(A1, fA[2], aG, 0,0,0); \
        f32x4_t aO = __builtin_amdgcn_mfma_f32_16x16x32_bf16(A2, fB[3], splat4(bv[3]), 0,0,0); \
        aO         = __builtin_amdgcn_mfma_f32_16x16x32_bf16(A1, fA[3], aO, 0,0,0); \
        f32x4_t h = lstm_act(aI, aF, aG, aO, cst);                             \
        h1f[WB][q4  ][u & 31] = (__bf16)h[0];                                  \
        h1f[WB][q4+1][u & 31] = (__bf16)h[1];                                  \
        h1f[WB][q4+2][u & 31] = (__bf16)h[2];                                  \
        h1f[WB][q4+3][u & 31] = (__bf16)h[3];                                  \
        if ((S) == TT-1) {                                                     \
            h1_last[(q4  )*32 + (u & 31)] = h[0];                              \
            h1_last[(q4+1)*32 + (u & 31)] = h[1];                              \
            h1_last[(q4+2)*32 + (u & 31)] = h[2];                              \
            h1_last[(q4+3)*32 + (u & 31)] = h[3];                              \
        }                                                                      \
    }                                                                          \
    __syncthreads();                                                           \
} while (0)

    STEP(-1, 1, 0, 1);          // prologue: layer0 t=0 only
    #pragma unroll 1
    for (int s = 0; s < TT; s += 2) {
        STEP(s,   0, 1, 0);
        STEP(s+1, 1, 0, 0);
    }
#undef STEP

    // ---- FC head (256 threads) ----
    #pragma unroll
    for (int rep = 0; rep < 4; ++rep) {
        int idx = tid + rep*256;          // 16*64 outputs
        int m = idx >> 6, uu = idx & 63;
        float a = bfc1[uu];
        for (int k = 0; k < HID; ++k) a += h1_last[m*32+k] * Wfc1[uu*HID+k];
        zbuf[m*64+uu] = fmaxf(a, 0.f);
    }
    __syncthreads();
    #pragma unroll
    for (int rep = 0; rep < 2; ++rep) {
        int idx = tid + rep*256;          // 16*32 outputs
        int m = idx >> 5, v = idx & 31;
        float a = bfc2[v];
        for (int k = 0; k < 64; ++k) a += zbuf[m*64+k] * Wfc2[v*64+k];
        z2buf[m*32+v] = fmaxf(a, 0.f);
    }
    __syncthreads();
    if (tid < 16) {
        float a = bfc3[0];
        for (int k = 0; k < 32; ++k) a += z2buf[tid*32+k] * Wfc3[k];
        out[bbase + tid] = fsigmoid(a);
    }
}

extern "C" void kernel_launch(void* const* d_in, const int* in_sizes, int n_in,
                              void* d_out, int out_size, void* d_ws, size_t ws_size,
                              hipStream_t stream) {
    const float* x    = (const float*)d_in[0];
    const float* Wih0 = (const float*)d_in[1];
    const float* Whh0 = (const float*)d_in[2];
    const float* bih0 = (const float*)d_in[3];
    const float* bhh0 = (const float*)d_in[4];
    const float* Wih1 = (const float*)d_in[5];
    const float* Whh1 = (const float*)d_in[6];
    const float* bih1 = (const float*)d_in[7];
    const float* bhh1 = (const float*)d_in[8];
    const float* Wfc1 = (const float*)d_in[9];
    const float* bfc1 = (const float*)d_in[10];
    const float* Wfc2 = (const float*)d_in[11];
    const float* bfc2 = (const float*)d_in[12];
    const float* Wfc3 = (const float*)d_in[13];
    const float* bfc3 = (const float*)d_in[14];
    float* outp = (float*)d_out;

    hipLaunchKernelGGL(lstm_fused, dim3(512), dim3(256), 0, stream,
        x, Wih0, Whh0, bih0, bhh0, Wih1, Whh1, bih1, bhh1,
        Wfc1, bfc1, Wfc2, bfc2, Wfc3, bfc3, outp);
}

// Round 4
// 272.568 us; speedup vs baseline: 1.2608x; 1.0119x over previous
//
#include <hip/hip_runtime.h>

#define TT   256
#define HID  30
#define LOG2E 1.4426950408889634f
#define HS   40   // h-row stride in bf16: 80B -> b128 A-frag reads are 2-way (free)

typedef __bf16 bf16x8_t __attribute__((ext_vector_type(8)));
typedef float  f32x4_t  __attribute__((ext_vector_type(4)));

__device__ __forceinline__ float fexp2(float x){
#if __has_builtin(__builtin_amdgcn_exp2f)
    return __builtin_amdgcn_exp2f(x);
#else
    return exp2f(x);
#endif
}
__device__ __forceinline__ float frcp(float x){
#if __has_builtin(__builtin_amdgcn_rcpf)
    return __builtin_amdgcn_rcpf(x);
#else
    return 1.f/x;
#endif
}
__device__ __forceinline__ float fsigmoid(float x){ return frcp(1.f + fexp2(-LOG2E*x)); }
__device__ __forceinline__ f32x4_t exp4(f32x4_t v){
    f32x4_t e; e[0]=fexp2(v[0]); e[1]=fexp2(v[1]); e[2]=fexp2(v[2]); e[3]=fexp2(v[3]); return e;
}
__device__ __forceinline__ f32x4_t rcp4(f32x4_t v){
    f32x4_t r; r[0]=frcp(v[0]); r[1]=frcp(v[1]); r[2]=frcp(v[2]); r[3]=frcp(v[3]); return r;
}
__device__ __forceinline__ f32x4_t splat4(float v){ f32x4_t r = {v,v,v,v}; return r; }

// Accs arrive pre-scaled into exp2 domain (scale folded into bf16 weights):
//   aI,aF,aO = -LOG2E*z ; aG = +2*LOG2E*z
// Merged-rcp activation: 28 trans insts (20 exp + 8 rcp) per 4-vec.
__device__ __forceinline__ f32x4_t lstm_act(f32x4_t aI, f32x4_t aF, f32x4_t aG,
                                            f32x4_t aO, f32x4_t& cst){
    f32x4_t eI = exp4(aI);
    f32x4_t eF = exp4(aF);
    f32x4_t eG = exp4(aG);
    f32x4_t eO = exp4(aO);
    f32x4_t D1 = eF + 1.f;
    f32x4_t tG = eG + 1.f;
    f32x4_t D2 = eI*tG + tG;           // (1+eI)(1+eG)
    f32x4_t r  = rcp4(D1*D2);
    f32x4_t f  = r*D2;                 // sigmoid(zf)
    f32x4_t p  = (eG - 1.f) * (r*D1);  // i*tanh(zg)
    cst = f*cst + p;
    f32x4_t cc;                        // clamp so e^{2c} can't overflow
    cc[0]=fminf(fmaxf(cst[0],-30.f),30.f);
    cc[1]=fminf(fmaxf(cst[1],-30.f),30.f);
    cc[2]=fminf(fmaxf(cst[2],-30.f),30.f);
    cc[3]=fminf(fmaxf(cst[3],-30.f),30.f);
    f32x4_t eC = exp4(cc * (2.f*LOG2E));
    f32x4_t tC = eC + 1.f;
    f32x4_t dn = eO*tC + tC;           // (1+eO)(1+eC)
    return (eC - 1.f) * rcp4(dn);
}

// R4 structure: 256-thread blocks, 4 waves (wv0,1 = L0 unit-halves, wv2,3 =
// L1 unit-halves). Grid 512, 2 blocks/CU. Skewed pipeline, double-buffered
// bf16 h tiles, 1 barrier/step.
// KEY CHANGE vs R3: the recurrence loop issues ZERO global-memory ops.
// __syncthreads compiles to s_waitcnt vmcnt(0)+s_barrier; the old per-step
// global x-prefetch forced an L2/HBM round-trip drain into EVERY step's
// barrier (~300-500cy of the 1950cy wall). x is now staged to LDS once
// (48KB f32), read per-step via broadcast ds_read_b128, and the input
// contribution bv + Wih0.x(t) is computed on the VALU as the MFMA C-operand.
__global__ __launch_bounds__(256, 2)
void lstm_fused(const float* __restrict__ x,
    const float* __restrict__ Wih0, const float* __restrict__ Whh0,
    const float* __restrict__ bih0, const float* __restrict__ bhh0,
    const float* __restrict__ Wih1, const float* __restrict__ Whh1,
    const float* __restrict__ bih1, const float* __restrict__ bhh1,
    const float* __restrict__ Wfc1, const float* __restrict__ bfc1,
    const float* __restrict__ Wfc2, const float* __restrict__ bfc2,
    const float* __restrict__ Wfc3, const float* __restrict__ bfc3,
    float* __restrict__ out)
{
    __shared__ __align__(16) float  xlds[TT][48];    // [t][row*3+c], 48KB
    __shared__ __align__(16) __bf16 h0f[2][16][HS];  // cols 30.. stay 0 (K pad)
    __shared__ __align__(16) __bf16 h1f[2][16][HS];
    __shared__ float h1_last[16*32];
    __shared__ float zbuf[16*64];
    __shared__ float z2buf[16*32];

    const int tid  = threadIdx.x;
    const int lane = tid & 63;
    const int wv   = tid >> 6;         // 0..3
    const int lay  = wv >> 1;          // 0: layer0, 1: layer1
    const int uh   = wv & 1;           // unit half
    const int n    = lane & 15;
    const int q    = lane >> 4;
    const int q4   = q*4;
    const int u    = uh*16 + n;        // hidden unit (col)
    const bool colok = (u < HID);
    const int uq   = colok ? u : 0;
    const int bbase = blockIdx.x * 16;

    // ---- resident per-gate B-fragments, scale folded into bf16 weights ----
    bf16x8_t fA[4], fB[4];   // fA: L0=Whh0 | L1=Wih1 ; fB: L1=Whh1
    float bv[4], wxv[4][3];  // bias and f32 input weights (L0 only uses wxv)
    {
        const float scl[4] = {-LOG2E, -LOG2E, 2.f*LOG2E, -LOG2E}; // i,f,g,o
        #pragma unroll
        for (int g = 0; g < 4; ++g) {
            const int row = g*HID + uq;
            const float sg = scl[g];
            bf16x8_t va{}, vb{};
            #pragma unroll
            for (int j = 0; j < 8; ++j) {
                int k = q*8 + j;
                float a = 0.f, b = 0.f;
                if (colok && k < HID) {
                    if (lay == 0) { a = Whh0[row*HID + k]; }
                    else          { a = Wih1[row*HID + k];  b = Whh1[row*HID + k]; }
                }
                va[j] = (__bf16)(sg*a);
                vb[j] = (__bf16)(sg*b);
            }
            fA[g] = va;  fB[g] = vb;
            float bb = 0.f;
            float w0 = 0.f, w1 = 0.f, w2 = 0.f;
            if (colok) {
                bb = lay ? (bih1[row] + bhh1[row]) : (bih0[row] + bhh0[row]);
                if (lay == 0) {
                    w0 = Wih0[row*3 + 0];
                    w1 = Wih0[row*3 + 1];
                    w2 = Wih0[row*3 + 2];
                }
            }
            bv[g] = sg*bb;
            wxv[g][0] = sg*w0;  wxv[g][1] = sg*w1;  wxv[g][2] = sg*w2;
        }
    }

    f32x4_t cst = {0.f,0.f,0.f,0.f};

    // zero h tiles (K-pad cols must be 0 forever)
    for (int i = tid; i < 2*16*HS; i += 256) {
        (&h0f[0][0][0])[i] = (__bf16)0.f;
        (&h1f[0][0][0])[i] = (__bf16)0.f;
    }
    // stage x block-slab into LDS: global coalesced float4, scattered ds_write
    {
        const float* xg = x + (size_t)bbase*(TT*3);
        for (int i4 = tid*4; i4 < 16*TT*3; i4 += 256*4) {
            int row = i4 / (TT*3), tc0 = i4 % (TT*3);
            f32x4_t v = *(const f32x4_t*)(xg + (size_t)row*(TT*3) + tc0);
            #pragma unroll
            for (int j = 0; j < 4; ++j) {
                int tc = tc0 + j;
                xlds[tc/3][row*3 + tc%3] = v[j];
            }
        }
    }
    __syncthreads();

#define STEP(S, RB, WB, FIRST) do {                                            \
    if (lay == 0) {                                                            \
        const int tcur = ((S)+1 < TT) ? (S)+1 : TT-1;                          \
        const float* xt = &xlds[tcur][q4*3];                                   \
        f32x4_t xv0 = *(const f32x4_t*)(xt);      /* r0c0 r0c1 r0c2 r1c0 */    \
        f32x4_t xv1 = *(const f32x4_t*)(xt + 4);  /* r1c1 r1c2 r2c0 r2c1 */    \
        f32x4_t xv2 = *(const f32x4_t*)(xt + 8);  /* r2c2 r3c0 r3c1 r3c2 */    \
        bf16x8_t A0 = *(const bf16x8_t*)(&h0f[RB][n][q*8]);                    \
        float xr[12];                                                          \
        xr[0]=xv0[0]; xr[1]=xv0[1]; xr[2]=xv0[2]; xr[3]=xv0[3];                \
        xr[4]=xv1[0]; xr[5]=xv1[1]; xr[6]=xv1[2]; xr[7]=xv1[3];                \
        xr[8]=xv2[0]; xr[9]=xv2[1]; xr[10]=xv2[2]; xr[11]=xv2[3];              \
        f32x4_t cin[4];                                                        \
        _Pragma("unroll")                                                      \
        for (int g = 0; g < 4; ++g) {                                          \
            f32x4_t c;                                                         \
            _Pragma("unroll")                                                  \
            for (int r2 = 0; r2 < 4; ++r2)                                     \
                c[r2] = bv[g] + wxv[g][0]*xr[3*r2]                             \
                              + wxv[g][1]*xr[3*r2+1]                           \
                              + wxv[g][2]*xr[3*r2+2];                          \
            cin[g] = c;                                                        \
        }                                                                      \
        f32x4_t aI = __builtin_amdgcn_mfma_f32_16x16x32_bf16(A0, fA[0], cin[0], 0,0,0); \
        f32x4_t aF = __builtin_amdgcn_mfma_f32_16x16x32_bf16(A0, fA[1], cin[1], 0,0,0); \
        f32x4_t aG = __builtin_amdgcn_mfma_f32_16x16x32_bf16(A0, fA[2], cin[2], 0,0,0); \
        f32x4_t aO = __builtin_amdgcn_mfma_f32_16x16x32_bf16(A0, fA[3], cin[3], 0,0,0); \
        f32x4_t h = lstm_act(aI, aF, aG, aO, cst);                             \
        h0f[WB][q4  ][u] = (__bf16)h[0];                                       \
        h0f[WB][q4+1][u] = (__bf16)h[1];                                       \
        h0f[WB][q4+2][u] = (__bf16)h[2];                                       \
        h0f[WB][q4+3][u] = (__bf16)h[3];                                       \
    } else if (!(FIRST)) {                                                     \
        bf16x8_t A1 = *(const bf16x8_t*)(&h0f[RB][n][q*8]);                    \
        bf16x8_t A2 = *(const bf16x8_t*)(&h1f[RB][n][q*8]);                    \
        f32x4_t aI = __builtin_amdgcn_mfma_f32_16x16x32_bf16(A2, fB[0], splat4(bv[0]), 0,0,0); \
        aI         = __builtin_amdgcn_mfma_f32_16x16x32_bf16(A1, fA[0], aI, 0,0,0); \
        f32x4_t aF = __builtin_amdgcn_mfma_f32_16x16x32_bf16(A2, fB[1], splat4(bv[1]), 0,0,0); \
        aF         = __builtin_amdgcn_mfma_f32_16x16x32_bf16(A1, fA[1], aF, 0,0,0); \
        f32x4_t aG = __builtin_amdgcn_mfma_f32_16x16x32_bf16(A2, fB[2], splat4(bv[2]), 0,0,0); \
        aG         = __builtin_amdgcn_mfma_f32_16x16x32_bf16(A1, fA[2], aG, 0,0,0); \
        f32x4_t aO = __builtin_amdgcn_mfma_f32_16x16x32_bf16(A2, fB[3], splat4(bv[3]), 0,0,0); \
        aO         = __builtin_amdgcn_mfma_f32_16x16x32_bf16(A1, fA[3], aO, 0,0,0); \
        f32x4_t h = lstm_act(aI, aF, aG, aO, cst);                             \
        h1f[WB][q4  ][u & 31] = (__bf16)h[0];                                  \
        h1f[WB][q4+1][u & 31] = (__bf16)h[1];                                  \
        h1f[WB][q4+2][u & 31] = (__bf16)h[2];                                  \
        h1f[WB][q4+3][u & 31] = (__bf16)h[3];                                  \
        if ((S) == TT-1) {                                                     \
            h1_last[(q4  )*32 + (u & 31)] = h[0];                              \
            h1_last[(q4+1)*32 + (u & 31)] = h[1];                              \
            h1_last[(q4+2)*32 + (u & 31)] = h[2];                              \
            h1_last[(q4+3)*32 + (u & 31)] = h[3];                              \
        }                                                                      \
    }                                                                          \
    __syncthreads();                                                           \
} while (0)

    STEP(-1, 1, 0, 1);          // prologue: layer0 t=0 only
    #pragma unroll 1
    for (int s = 0; s < TT; s += 2) {
        STEP(s,   0, 1, 0);
        STEP(s+1, 1, 0, 0);
    }
#undef STEP

    // ---- FC head (256 threads) ----
    #pragma unroll
    for (int rep = 0; rep < 4; ++rep) {
        int idx = tid + rep*256;          // 16*64 outputs
        int m = idx >> 6, uu = idx & 63;
        float a = bfc1[uu];
        for (int k = 0; k < HID; ++k) a += h1_last[m*32+k] * Wfc1[uu*HID+k];
        zbuf[m*64+uu] = fmaxf(a, 0.f);
    }
    __syncthreads();
    #pragma unroll
    for (int rep = 0; rep < 2; ++rep) {
        int idx = tid + rep*256;          // 16*32 outputs
        int m = idx >> 5, v = idx & 31;
        float a = bfc2[v];
        for (int k = 0; k < 64; ++k) a += zbuf[m*64+k] * Wfc2[v*64+k];
        z2buf[m*32+v] = fmaxf(a, 0.f);
    }
    __syncthreads();
    if (tid < 16) {
        float a = bfc3[0];
        for (int k = 0; k < 32; ++k) a += z2buf[tid*32+k] * Wfc3[k];
        out[bbase + tid] = fsigmoid(a);
    }
}

extern "C" void kernel_launch(void* const* d_in, const int* in_sizes, int n_in,
                              void* d_out, int out_size, void* d_ws, size_t ws_size,
                              hipStream_t stream) {
    const float* x    = (const float*)d_in[0];
    const float* Wih0 = (const float*)d_in[1];
    const float* Whh0 = (const float*)d_in[2];
    const float* bih0 = (const float*)d_in[3];
    const float* bhh0 = (const float*)d_in[4];
    const float* Wih1 = (const float*)d_in[5];
    const float* Whh1 = (const float*)d_in[6];
    const float* bih1 = (const float*)d_in[7];
    const float* bhh1 = (const float*)d_in[8];
    const float* Wfc1 = (const float*)d_in[9];
    const float* bfc1 = (const float*)d_in[10];
    const float* Wfc2 = (const float*)d_in[11];
    const float* bfc2 = (const float*)d_in[12];
    const float* Wfc3 = (const float*)d_in[13];
    const float* bfc3 = (const float*)d_in[14];
    float* outp = (float*)d_out;

    hipLaunchKernelGGL(lstm_fused, dim3(512), dim3(256), 0, stream,
        x, Wih0, Whh0, bih0, bhh0, Wih1, Whh1, bih1, bhh1,
        Wfc1, bfc1, Wfc2, bfc2, Wfc3, bfc3, outp);
}